// Round 3
// baseline (163.541 us; speedup 1.0000x reference)
//
#include <hip/hip_runtime.h>
#include <math.h>

#define BLOCK 256

// ---------------------------------------------------------------------------
// Pass A: pack refs as (x, y, z, r2) float4 so the scan loop fetches one
// candidate with a single wave-uniform s_load_dwordx4 (refs live in SGPRs).
// r2 op order matches np.sum(ref*ref, axis=-1): (x*x + y*y) + z*z
// ---------------------------------------------------------------------------
__global__ __launch_bounds__(BLOCK) void prep_refs(
    const float* __restrict__ ref, float4* __restrict__ refs4, int Nr) {
#pragma clang fp contract(off)
    int j = blockIdx.x * BLOCK + threadIdx.x;
    if (j < Nr) {
        float x = ref[j * 3 + 0];
        float y = ref[j * 3 + 1];
        float z = ref[j * 3 + 2];
        float r2 = (x * x + y * y) + z * z;
        refs4[j] = make_float4(x, y, z, r2);
    }
}

// ---------------------------------------------------------------------------
// Pass B: one thread = one query; scans one ref chunk (block-uniform j ->
// scalar s_load path). Running top-3 kept in registers.
//
// Numerics identical to reference:
//   dot = fmaf(qz,rz, fmaf(qy,ry, qx*rx))
//   d2  = fmaf(-2, dot, q2 + r2)   == (q2+r2) - 2*dot  (2*dot exact, 1 rnd)
//   d   = max(d2, 0)
//
// Selection: FULLY BRANCHLESS in-place insertion network, 13 VALU flat:
//   level l: c = d < e_l; e_l = min(d, e_l); displaced = max(d, e_l_old);
//            i_l = c ? j : i_l; displaced_idx = c ? i_l_old : j
// Tie (d == e_l): c false -> existing (earlier-index) entry stays, new value
// cascades down == jax top_k stable tie-break with ascending-j scan.
// ---------------------------------------------------------------------------
__global__ __launch_bounds__(BLOCK) void knn_scan(
    const float* __restrict__ qpts, const float4* __restrict__ refs4,
    float* __restrict__ cd, int* __restrict__ ci,
    int Nq, int Nr, int chunk) {
#pragma clang fp contract(off)
    int qi = blockIdx.x * BLOCK + threadIdx.x;
    int c  = blockIdx.y;
    int jbeg = c * chunk;
    int jend = jbeg + chunk;
    if (jend > Nr) jend = Nr;

    float qx = 0.f, qy = 0.f, qz = 0.f;
    if (qi < Nq) {
        qx = qpts[qi * 3 + 0];
        qy = qpts[qi * 3 + 1];
        qz = qpts[qi * 3 + 2];
    }
    float q2 = (qx * qx + qy * qy) + qz * qz;

    const float FINF = __builtin_inff();
    float e0 = FINF, e1 = FINF, e2 = FINF;
    int   i0 = 0x7fffffff, i1 = 0x7fffffff, i2 = 0x7fffffff;

#pragma unroll 4
    for (int j = jbeg; j < jend; ++j) {
        float4 r = refs4[j];               // wave-uniform -> s_load_dwordx4
        float t = qx * r.x;
        t = fmaf(qy, r.y, t);
        t = fmaf(qz, r.z, t);
        float a = q2 + r.w;
        float d = fmaxf(fmaf(-2.0f, t, a), 0.0f);

        // level 0
        bool  c0 = d < e0;
        float m0 = fminf(d, e0);
        float x0 = fmaxf(d, e0);           // displaced value
        int   y0 = c0 ? i0 : j;            // displaced index
        i0 = c0 ? j : i0;
        e0 = m0;
        // level 1
        bool  c1 = x0 < e1;
        float m1 = fminf(x0, e1);
        float x1 = fmaxf(x0, e1);
        int   y1 = c1 ? i1 : y0;
        i1 = c1 ? y0 : i1;
        e1 = m1;
        // level 2
        bool  c2 = x1 < e2;
        e2 = fminf(x1, e2);
        i2 = c2 ? y1 : i2;
    }

    if (qi < Nq) {
        size_t base = (size_t)(c * 3) * (size_t)Nq + (size_t)qi; // [c][slot][q]
        cd[base]                 = e0;
        cd[base + (size_t)Nq]    = e1;
        cd[base + 2*(size_t)Nq]  = e2;
        ci[base]                 = i0;
        ci[base + (size_t)Nq]    = i1;
        ci[base + 2*(size_t)Nq]  = i2;
    }
}

// ---------------------------------------------------------------------------
// Pass C: merge nCand candidates per query (lexicographic (d, idx) to match
// top_k tie behavior across chunks), then dist/weights/normalize/gather in
// reference op order:
//   dist = sqrt(d2c); w = 1/(dist + 1e-8); w /= ((w0+w1)+w2);
//   out  = (w0*f0 + w1*f1) + w2*f2   per component
// ---------------------------------------------------------------------------
__global__ __launch_bounds__(BLOCK) void knn_finish(
    const float* __restrict__ flow, const float* __restrict__ cd,
    const int* __restrict__ ci, float* __restrict__ out,
    int Nq, int nCand) {
#pragma clang fp contract(off)
    int qi = blockIdx.x * BLOCK + threadIdx.x;
    if (qi >= Nq) return;

    const float FINF = __builtin_inff();
    float bd0 = FINF, bd1 = FINF, bd2 = FINF;
    int   bi0 = 0x7fffffff, bi1 = 0x7fffffff, bi2 = 0x7fffffff;

    for (int s = 0; s < nCand; ++s) {
        float d  = cd[(size_t)s * (size_t)Nq + (size_t)qi];
        int   ix = ci[(size_t)s * (size_t)Nq + (size_t)qi];
        bool lt2 = (d < bd2) || (d == bd2 && ix < bi2);
        bool lt1 = (d < bd1) || (d == bd1 && ix < bi1);
        bool lt0 = (d < bd0) || (d == bd0 && ix < bi0);
        float nd2 = lt1 ? bd1 : (lt2 ? d : bd2);
        int   ni2 = lt1 ? bi1 : (lt2 ? ix : bi2);
        float nd1 = lt0 ? bd0 : (lt1 ? d : bd1);
        int   ni1 = lt0 ? bi0 : (lt1 ? ix : bi1);
        float nd0 = lt0 ? d  : bd0;
        int   ni0 = lt0 ? ix : bi0;
        bd0 = nd0; bd1 = nd1; bd2 = nd2;
        bi0 = ni0; bi1 = ni1; bi2 = ni2;
    }

    float s0 = sqrtf(bd0);
    float s1 = sqrtf(bd1);
    float s2 = sqrtf(bd2);
    float w0 = 1.0f / (s0 + 1e-8f);
    float w1 = 1.0f / (s1 + 1e-8f);
    float w2 = 1.0f / (s2 + 1e-8f);
    float wsum = (w0 + w1) + w2;
    w0 = w0 / wsum;
    w1 = w1 / wsum;
    w2 = w2 / wsum;

    float f0x = flow[bi0 * 3 + 0], f0y = flow[bi0 * 3 + 1], f0z = flow[bi0 * 3 + 2];
    float f1x = flow[bi1 * 3 + 0], f1y = flow[bi1 * 3 + 1], f1z = flow[bi1 * 3 + 2];
    float f2x = flow[bi2 * 3 + 0], f2y = flow[bi2 * 3 + 1], f2z = flow[bi2 * 3 + 2];

    out[qi * 3 + 0] = (w0 * f0x + w1 * f1x) + w2 * f2x;
    out[qi * 3 + 1] = (w0 * f0y + w1 * f1y) + w2 * f2y;
    out[qi * 3 + 2] = (w0 * f0z + w1 * f1z) + w2 * f2z;
}

extern "C" void kernel_launch(void* const* d_in, const int* in_sizes, int n_in,
                              void* d_out, int out_size, void* d_ws, size_t ws_size,
                              hipStream_t stream) {
    const float* q    = (const float*)d_in[0];
    const float* ref  = (const float*)d_in[1];
    const float* flow = (const float*)d_in[2];
    float* out = (float*)d_out;

    int Nq = in_sizes[0] / 3;
    int Nr = in_sizes[1] / 3;

    // Pick CHUNKS to fit workspace: refs4 + CHUNKS*3*Nq*(float+int)
    int chunks = 32;
    while (chunks > 4) {
        size_t need = (size_t)Nr * sizeof(float4)
                    + (size_t)chunks * 3 * (size_t)Nq * (sizeof(float) + sizeof(int));
        if (need <= ws_size) break;
        chunks >>= 1;
    }

    char* ws = (char*)d_ws;
    float4* refs4 = (float4*)ws;
    size_t off = (size_t)Nr * sizeof(float4);
    float* cd = (float*)(ws + off);
    off += (size_t)chunks * 3 * (size_t)Nq * sizeof(float);
    int* ci = (int*)(ws + off);

    int chunk = (Nr + chunks - 1) / chunks;

    prep_refs<<<(Nr + BLOCK - 1) / BLOCK, BLOCK, 0, stream>>>(ref, refs4, Nr);

    dim3 grid((Nq + BLOCK - 1) / BLOCK, chunks);
    knn_scan<<<grid, BLOCK, 0, stream>>>(q, refs4, cd, ci, Nq, Nr, chunk);

    knn_finish<<<(Nq + BLOCK - 1) / BLOCK, BLOCK, 0, stream>>>(
        flow, cd, ci, out, Nq, chunks * 3);
}

// Round 4
// 152.536 us; speedup vs baseline: 1.0721x; 1.0721x over previous
//
#include <hip/hip_runtime.h>
#include <math.h>

#define BLOCK 256
#define Q 4   // queries per thread

// ---------------------------------------------------------------------------
// Pass A: pack refs as (x, y, z, r2). r2 op order matches
// np.sum(ref*ref, axis=-1): (x*x + y*y) + z*z
// ---------------------------------------------------------------------------
__global__ __launch_bounds__(BLOCK) void prep_refs(
    const float* __restrict__ ref, float4* __restrict__ refs4, int Nr) {
#pragma clang fp contract(off)
    int j = blockIdx.x * BLOCK + threadIdx.x;
    if (j < Nr) {
        float x = ref[j * 3 + 0];
        float y = ref[j * 3 + 1];
        float z = ref[j * 3 + 2];
        float r2 = (x * x + y * y) + z * z;
        refs4[j] = make_float4(x, y, z, r2);
    }
}

// ---------------------------------------------------------------------------
// Pass B: REGISTER-TILED: each thread owns Q queries, scans one ref chunk.
// The per-iteration fixed cost (wave-uniform refs4[j] fetch, waitcnt, loop
// bookkeeping) is amortized over Q*unroll pairs — R1-R3 showed that cost,
// not VALU count, was the limiter.
//
// Numerics identical to the passing version:
//   t  = fmaf(qz,rz, fmaf(qy,ry, qx*rx))
//   d  = max(fmaf(-2, t, q2 + r2), 0)
// Insert: 11-op branchless network (3 v_cmp + min/med3/med3 + 5 cndmask),
// invariant e0<=e1<=e2. Tie (d == e_l) -> c_l false -> existing earlier-index
// entry stays, new cascades below == jax top_k stable tie-break (ascending j).
// ---------------------------------------------------------------------------
__global__ __launch_bounds__(BLOCK, 4) void knn_scan(
    const float* __restrict__ qpts, const float4* __restrict__ refs4,
    float* __restrict__ cd, int* __restrict__ ci,
    int Nq, int qstride, int Nr, int chunk) {
#pragma clang fp contract(off)
    int t = blockIdx.x * BLOCK + threadIdx.x;   // 0..qstride-1
    int c = blockIdx.y;
    int jbeg = c * chunk;
    int jend = jbeg + chunk;
    if (jend > Nr) jend = Nr;

    float qx[Q], qy[Q], qz[Q], q2[Q];
    float e0[Q], e1[Q], e2[Q];
    int   i0[Q], i1[Q], i2[Q];

    const float FINF = __builtin_inff();
#pragma unroll
    for (int s = 0; s < Q; ++s) {
        int qi = t + s * qstride;
        float x = 0.f, y = 0.f, z = 0.f;
        if (qi < Nq) {
            x = qpts[qi * 3 + 0];
            y = qpts[qi * 3 + 1];
            z = qpts[qi * 3 + 2];
        }
        qx[s] = x; qy[s] = y; qz[s] = z;
        q2[s] = (x * x + y * y) + z * z;
        e0[s] = FINF; e1[s] = FINF; e2[s] = FINF;
        i0[s] = 0x7fffffff; i1[s] = 0x7fffffff; i2[s] = 0x7fffffff;
    }

#pragma unroll 4
    for (int j = jbeg; j < jend; ++j) {
        float4 r = refs4[j];               // wave-uniform -> scalar load
#pragma unroll
        for (int s = 0; s < Q; ++s) {
            float tdot = qx[s] * r.x;
            tdot = fmaf(qy[s], r.y, tdot);
            tdot = fmaf(qz[s], r.z, tdot);
            float a = q2[s] + r.w;
            float d = fmaxf(fmaf(-2.0f, tdot, a), 0.0f);

            bool c0 = d < e0[s];
            bool c1 = d < e1[s];
            bool c2 = d < e2[s];
            int ni0 = c0 ? j : i0[s];
            int ni1 = c0 ? i0[s] : (c1 ? j : i1[s]);
            int ni2 = c1 ? i1[s] : (c2 ? j : i2[s]);
            float ne0 = fminf(d, e0[s]);
            float ne1 = __builtin_amdgcn_fmed3f(d, e0[s], e1[s]);
            float ne2 = __builtin_amdgcn_fmed3f(d, e1[s], e2[s]);
            e0[s] = ne0; e1[s] = ne1; e2[s] = ne2;
            i0[s] = ni0; i1[s] = ni1; i2[s] = ni2;
        }
    }

#pragma unroll
    for (int s = 0; s < Q; ++s) {
        int qi = t + s * qstride;
        if (qi < Nq) {
            size_t base = (size_t)(c * 3) * (size_t)Nq + (size_t)qi; // [c][slot][q]
            cd[base]                = e0[s];
            cd[base + (size_t)Nq]   = e1[s];
            cd[base + 2*(size_t)Nq] = e2[s];
            ci[base]                = i0[s];
            ci[base + (size_t)Nq]   = i1[s];
            ci[base + 2*(size_t)Nq] = i2[s];
        }
    }
}

// ---------------------------------------------------------------------------
// Pass C: merge nCand candidates per query. Candidates arrive in (chunk asc,
// slot asc) order == globally ascending index for equal distances, and slots
// within a chunk are already (d asc, idx asc). So a strict-'<' insertion
// network reproduces the full lexicographic (d, idx) top-3 == jax top_k.
// Then dist/weights/normalize/gather in reference op order.
// ---------------------------------------------------------------------------
__global__ __launch_bounds__(BLOCK) void knn_finish(
    const float* __restrict__ flow, const float* __restrict__ cd,
    const int* __restrict__ ci, float* __restrict__ out,
    int Nq, int nCand) {
#pragma clang fp contract(off)
    int qi = blockIdx.x * BLOCK + threadIdx.x;
    if (qi >= Nq) return;

    const float FINF = __builtin_inff();
    float bd0 = FINF, bd1 = FINF, bd2 = FINF;
    int   bi0 = 0x7fffffff, bi1 = 0x7fffffff, bi2 = 0x7fffffff;

    for (int s = 0; s < nCand; ++s) {
        float d  = cd[(size_t)s * (size_t)Nq + (size_t)qi];
        int   ix = ci[(size_t)s * (size_t)Nq + (size_t)qi];
        bool c0 = d < bd0;
        bool c1 = d < bd1;
        bool c2 = d < bd2;
        int ni0 = c0 ? ix : bi0;
        int ni1 = c0 ? bi0 : (c1 ? ix : bi1);
        int ni2 = c1 ? bi1 : (c2 ? ix : bi2);
        float nd0 = fminf(d, bd0);
        float nd1 = __builtin_amdgcn_fmed3f(d, bd0, bd1);
        float nd2 = __builtin_amdgcn_fmed3f(d, bd1, bd2);
        bd0 = nd0; bd1 = nd1; bd2 = nd2;
        bi0 = ni0; bi1 = ni1; bi2 = ni2;
    }

    float s0 = sqrtf(bd0);
    float s1 = sqrtf(bd1);
    float s2 = sqrtf(bd2);
    float w0 = 1.0f / (s0 + 1e-8f);
    float w1 = 1.0f / (s1 + 1e-8f);
    float w2 = 1.0f / (s2 + 1e-8f);
    float wsum = (w0 + w1) + w2;
    w0 = w0 / wsum;
    w1 = w1 / wsum;
    w2 = w2 / wsum;

    float f0x = flow[bi0 * 3 + 0], f0y = flow[bi0 * 3 + 1], f0z = flow[bi0 * 3 + 2];
    float f1x = flow[bi1 * 3 + 0], f1y = flow[bi1 * 3 + 1], f1z = flow[bi1 * 3 + 2];
    float f2x = flow[bi2 * 3 + 0], f2y = flow[bi2 * 3 + 1], f2z = flow[bi2 * 3 + 2];

    out[qi * 3 + 0] = (w0 * f0x + w1 * f1x) + w2 * f2x;
    out[qi * 3 + 1] = (w0 * f0y + w1 * f1y) + w2 * f2y;
    out[qi * 3 + 2] = (w0 * f0z + w1 * f1z) + w2 * f2z;
}

extern "C" void kernel_launch(void* const* d_in, const int* in_sizes, int n_in,
                              void* d_out, int out_size, void* d_ws, size_t ws_size,
                              hipStream_t stream) {
    const float* q    = (const float*)d_in[0];
    const float* ref  = (const float*)d_in[1];
    const float* flow = (const float*)d_in[2];
    float* out = (float*)d_out;

    int Nq = in_sizes[0] / 3;
    int Nr = in_sizes[1] / 3;

    // chunks: want >= 1024 blocks for occupancy; fall back if ws too small.
    int chunks = 64;
    while (chunks > 4) {
        size_t need = (size_t)Nr * sizeof(float4)
                    + (size_t)chunks * 3 * (size_t)Nq * (sizeof(float) + sizeof(int));
        if (need <= ws_size) break;
        chunks >>= 1;
    }

    char* ws = (char*)d_ws;
    float4* refs4 = (float4*)ws;
    size_t off = (size_t)Nr * sizeof(float4);
    float* cd = (float*)(ws + off);
    off += (size_t)chunks * 3 * (size_t)Nq * sizeof(float);
    int* ci = (int*)(ws + off);

    int chunk = (Nr + chunks - 1) / chunks;
    int qstride = (Nq + Q - 1) / Q;

    prep_refs<<<(Nr + BLOCK - 1) / BLOCK, BLOCK, 0, stream>>>(ref, refs4, Nr);

    dim3 grid((qstride + BLOCK - 1) / BLOCK, chunks);
    knn_scan<<<grid, BLOCK, 0, stream>>>(q, refs4, cd, ci, Nq, qstride, Nr, chunk);

    knn_finish<<<(Nq + BLOCK - 1) / BLOCK, BLOCK, 0, stream>>>(
        flow, cd, ci, out, Nq, chunks * 3);
}

// Round 5
// 138.176 us; speedup vs baseline: 1.1836x; 1.1039x over previous
//
#include <hip/hip_runtime.h>
#include <math.h>

#define BLOCK 256
#define CHUNKS 4

// ---------------------------------------------------------------------------
// Pass A: pack refs as (x, y, z, r2). r2 op order matches
// np.sum(ref*ref, axis=-1): (x*x + y*y) + z*z
// ---------------------------------------------------------------------------
__global__ __launch_bounds__(BLOCK) void prep_refs(
    const float* __restrict__ ref, float4* __restrict__ refs4, int Nr) {
#pragma clang fp contract(off)
    int j = blockIdx.x * BLOCK + threadIdx.x;
    if (j < Nr) {
        float x = ref[j * 3 + 0];
        float y = ref[j * 3 + 1];
        float z = ref[j * 3 + 2];
        float r2 = (x * x + y * y) + z * z;
        refs4[j] = make_float4(x, y, z, r2);
    }
}

// lexicographic (d, idx) less-than: jax top_k tie semantics
__device__ __forceinline__ bool lexlt(float d, int jd, float e, int je) {
    return (d < e) || ((d == e) && (jd < je));
}

// ---------------------------------------------------------------------------
// Pass B: 8x8 lane grid. lane = qid (lane&7) x slot (lane>>3).
// One vector load (8 distinct float4, 8-way broadcast) per wave-iteration
// serves 64 pairs — NO scalar loads in the hot loop (R2-R4 showed the
// scalar-memory path was the pinned bottleneck at ~125 µs).
//
// Numerics: t = fmaf(qz,rz, fmaf(qy,ry, qx*rx)); d2 = fmaf(-2,t, q2+r2)
// (== (q2+r2) - 2t exactly). Clamp to 0 deferred to the 3 survivors.
// Within-lane: strict '<' insert, ascending j (stride 8) -> earliest index
// wins ties. Cross-lane: 3-stage shfl_xor butterfly with lexicographic
// (d, idx) inserts -> smallest index wins ties == jax top_k.
// ---------------------------------------------------------------------------
__global__ __launch_bounds__(BLOCK, 8) void knn_scan(
    const float* __restrict__ qpts, const float4* __restrict__ refs4,
    float* __restrict__ cd, int* __restrict__ ci,
    int Nq, int Nr, int chunkRefs) {
#pragma clang fp contract(off)
    int lane = threadIdx.x & 63;
    int wave = threadIdx.x >> 6;
    int qid  = lane & 7;        // query within wave
    int slot = lane >> 3;       // ref slot 0..7
    int qbase = blockIdx.x * 32 + wave * 8;
    int qi = qbase + qid;

    int c = blockIdx.y;
    int jbeg = c * chunkRefs;
    int jend = jbeg + chunkRefs;
    if (jend > Nr) jend = Nr;

    float qx = 0.f, qy = 0.f, qz = 0.f;
    if (qi < Nq) {
        qx = qpts[qi * 3 + 0];
        qy = qpts[qi * 3 + 1];
        qz = qpts[qi * 3 + 2];
    }
    float q2 = (qx * qx + qy * qy) + qz * qz;

    const float FINF = __builtin_inff();
    float e0 = FINF, e1 = FINF, e2 = FINF;
    int   i0 = 0x7fffffff, i1 = 0x7fffffff, i2 = 0x7fffffff;

    int nref  = jend - jbeg;
    int nfull = nref >> 3;                 // full groups of 8 refs
    const float4* __restrict__ p = refs4 + jbeg + slot;

#pragma unroll 4
    for (int t = 0; t < nfull; ++t) {
        float4 r = p[(size_t)t * 8];       // vector load, 8-way broadcast
        int j = jbeg + t * 8 + slot;
        float td = qx * r.x;
        td = fmaf(qy, r.y, td);
        td = fmaf(qz, r.z, td);
        float a = q2 + r.w;
        float d = fmaf(-2.0f, td, a);      // unclamped d2

        bool c0 = d < e0;
        bool c1 = d < e1;
        bool c2 = d < e2;
        int ni0 = c0 ? j : i0;
        int ni1 = c0 ? i0 : (c1 ? j : i1);
        int ni2 = c1 ? i1 : (c2 ? j : i2);
        float ne0 = fminf(d, e0);
        float ne1 = __builtin_amdgcn_fmed3f(d, e0, e1);
        float ne2 = __builtin_amdgcn_fmed3f(d, e1, e2);
        e0 = ne0; e1 = ne1; e2 = ne2;
        i0 = ni0; i1 = ni1; i2 = ni2;
    }
    // tail (nref not divisible by 8)
    {
        int j = jbeg + nfull * 8 + slot;
        if (j < jend) {
            float4 r = refs4[j];
            float td = qx * r.x;
            td = fmaf(qy, r.y, td);
            td = fmaf(qz, r.z, td);
            float a = q2 + r.w;
            float d = fmaf(-2.0f, td, a);
            bool c0 = d < e0;
            bool c1 = d < e1;
            bool c2 = d < e2;
            int ni0 = c0 ? j : i0;
            int ni1 = c0 ? i0 : (c1 ? j : i1);
            int ni2 = c1 ? i1 : (c2 ? j : i2);
            float ne0 = fminf(d, e0);
            float ne1 = __builtin_amdgcn_fmed3f(d, e0, e1);
            float ne2 = __builtin_amdgcn_fmed3f(d, e1, e2);
            e0 = ne0; e1 = ne1; e2 = ne2;
            i0 = ni0; i1 = ni1; i2 = ni2;
        }
    }

    // clamp survivors to match reference max(d2, 0)
    e0 = fmaxf(e0, 0.0f);
    e1 = fmaxf(e1, 0.0f);
    e2 = fmaxf(e2, 0.0f);

    // cross-lane merge across the 8 slots of each query (masks 8,16,32)
#pragma unroll
    for (int m = 8; m < 64; m <<= 1) {
        float f0 = __shfl_xor(e0, m, 64);
        float f1 = __shfl_xor(e1, m, 64);
        float f2 = __shfl_xor(e2, m, 64);
        int   g0 = __shfl_xor(i0, m, 64);
        int   g1 = __shfl_xor(i1, m, 64);
        int   g2 = __shfl_xor(i2, m, 64);
#pragma unroll
        for (int s = 0; s < 3; ++s) {
            float d = (s == 0) ? f0 : (s == 1) ? f1 : f2;
            int   j = (s == 0) ? g0 : (s == 1) ? g1 : g2;
            bool c0 = lexlt(d, j, e0, i0);
            bool c1 = lexlt(d, j, e1, i1);
            bool c2 = lexlt(d, j, e2, i2);
            int ni0 = c0 ? j : i0;
            int ni1 = c0 ? i0 : (c1 ? j : i1);
            int ni2 = c1 ? i1 : (c2 ? j : i2);
            float ne0 = fminf(d, e0);
            float ne1 = __builtin_amdgcn_fmed3f(d, e0, e1);
            float ne2 = __builtin_amdgcn_fmed3f(d, e1, e2);
            e0 = ne0; e1 = ne1; e2 = ne2;
            i0 = ni0; i1 = ni1; i2 = ni2;
        }
    }

    if (qi < Nq && slot == 0) {            // lanes 0..7 write
        size_t base = (size_t)(c * 3) * (size_t)Nq + (size_t)qi;
        cd[base]                = e0;
        cd[base + (size_t)Nq]   = e1;
        cd[base + 2*(size_t)Nq] = e2;
        ci[base]                = i0;
        ci[base + (size_t)Nq]   = i1;
        ci[base + 2*(size_t)Nq] = i2;
    }
}

// ---------------------------------------------------------------------------
// Pass C: merge nCand candidates per query. Traversal order (chunk asc, slot
// asc) is lexicographic, so strict '<' insertion preserves jax top_k tie
// semantics. Then dist/weights/normalize/gather in reference op order.
// ---------------------------------------------------------------------------
__global__ __launch_bounds__(BLOCK) void knn_finish(
    const float* __restrict__ flow, const float* __restrict__ cd,
    const int* __restrict__ ci, float* __restrict__ out,
    int Nq, int nCand) {
#pragma clang fp contract(off)
    int qi = blockIdx.x * BLOCK + threadIdx.x;
    if (qi >= Nq) return;

    const float FINF = __builtin_inff();
    float bd0 = FINF, bd1 = FINF, bd2 = FINF;
    int   bi0 = 0x7fffffff, bi1 = 0x7fffffff, bi2 = 0x7fffffff;

    for (int s = 0; s < nCand; ++s) {
        float d  = cd[(size_t)s * (size_t)Nq + (size_t)qi];
        int   ix = ci[(size_t)s * (size_t)Nq + (size_t)qi];
        bool c0 = d < bd0;
        bool c1 = d < bd1;
        bool c2 = d < bd2;
        int ni0 = c0 ? ix : bi0;
        int ni1 = c0 ? bi0 : (c1 ? ix : bi1);
        int ni2 = c1 ? bi1 : (c2 ? ix : bi2);
        float nd0 = fminf(d, bd0);
        float nd1 = __builtin_amdgcn_fmed3f(d, bd0, bd1);
        float nd2 = __builtin_amdgcn_fmed3f(d, bd1, bd2);
        bd0 = nd0; bd1 = nd1; bd2 = nd2;
        bi0 = ni0; bi1 = ni1; bi2 = ni2;
    }

    float s0 = sqrtf(bd0);
    float s1 = sqrtf(bd1);
    float s2 = sqrtf(bd2);
    float w0 = 1.0f / (s0 + 1e-8f);
    float w1 = 1.0f / (s1 + 1e-8f);
    float w2 = 1.0f / (s2 + 1e-8f);
    float wsum = (w0 + w1) + w2;
    w0 = w0 / wsum;
    w1 = w1 / wsum;
    w2 = w2 / wsum;

    float f0x = flow[bi0 * 3 + 0], f0y = flow[bi0 * 3 + 1], f0z = flow[bi0 * 3 + 2];
    float f1x = flow[bi1 * 3 + 0], f1y = flow[bi1 * 3 + 1], f1z = flow[bi1 * 3 + 2];
    float f2x = flow[bi2 * 3 + 0], f2y = flow[bi2 * 3 + 1], f2z = flow[bi2 * 3 + 2];

    out[qi * 3 + 0] = (w0 * f0x + w1 * f1x) + w2 * f2x;
    out[qi * 3 + 1] = (w0 * f0y + w1 * f1y) + w2 * f2y;
    out[qi * 3 + 2] = (w0 * f0z + w1 * f1z) + w2 * f2z;
}

extern "C" void kernel_launch(void* const* d_in, const int* in_sizes, int n_in,
                              void* d_out, int out_size, void* d_ws, size_t ws_size,
                              hipStream_t stream) {
    const float* q    = (const float*)d_in[0];
    const float* ref  = (const float*)d_in[1];
    const float* flow = (const float*)d_in[2];
    float* out = (float*)d_out;

    int Nq = in_sizes[0] / 3;
    int Nr = in_sizes[1] / 3;

    int chunks = CHUNKS;
    char* ws = (char*)d_ws;
    float4* refs4 = (float4*)ws;
    size_t off = (size_t)Nr * sizeof(float4);
    float* cd = (float*)(ws + off);
    off += (size_t)chunks * 3 * (size_t)Nq * sizeof(float);
    int* ci = (int*)(ws + off);

    int chunkRefs = (Nr + chunks - 1) / chunks;

    prep_refs<<<(Nr + BLOCK - 1) / BLOCK, BLOCK, 0, stream>>>(ref, refs4, Nr);

    int qPerBlock = 32;  // 4 waves x 8 queries
    dim3 grid((Nq + qPerBlock - 1) / qPerBlock, chunks);
    knn_scan<<<grid, BLOCK, 0, stream>>>(q, refs4, cd, ci, Nq, Nr, chunkRefs);

    knn_finish<<<(Nq + BLOCK - 1) / BLOCK, BLOCK, 0, stream>>>(
        flow, cd, ci, out, Nq, chunks * 3);
}